// Round 17
// baseline (188.707 us; speedup 1.0000x reference)
//
#include <hip/hip_runtime.h>
#include <hip/hip_bf16.h>
#include <stdint.h>

#define S_LEN 2048
#define HID 2880
#define NH 64
#define NKV 8
#define HD 64
#define NQ (NH * HD)     // 4096
#define NKVD (NKV * HD)  // 512
#define SCALE 0.125f

typedef unsigned short u16;
typedef __attribute__((ext_vector_type(8))) short short8;
typedef __attribute__((ext_vector_type(4))) float floatx4;

__device__ __forceinline__ u16 f2bf(float f) {
  union { float f; unsigned u; } x; x.f = f;
  unsigned r = x.u + 0x7fffu + ((x.u >> 16) & 1u);
  return (u16)(r >> 16);
}

// global -> LDS async copy, 16B per lane. LDS dest is wave-uniform base;
// HW writes lane i at base + i*16.
__device__ __forceinline__ void gl2lds16(const void* g, void* l) {
  __builtin_amdgcn_global_load_lds(
      (__attribute__((address_space(1))) unsigned int*)(uintptr_t)g,
      (__attribute__((address_space(3))) unsigned int*)(unsigned int)(uintptr_t)l,
      16, 0, 0);
}

// ---------------- merged preprocessing: hs convert + all 4 transposes ----------------
__global__ void k_pre(const float* __restrict__ hs, u16* __restrict__ hsb,
                      const float* __restrict__ wq, const float* __restrict__ wk,
                      const float* __restrict__ wv, const float* __restrict__ wo,
                      u16* __restrict__ wqt, u16* __restrict__ wkt,
                      u16* __restrict__ wvt, u16* __restrict__ wot) {
  int b = blockIdx.x;
  const int ncv = (S_LEN * HID / 4) / 256;    // 5760 convert blocks
  if (b < ncv) {
    int i = b * 256 + threadIdx.x;
    float4 v = ((const float4*)hs)[i];
    ushort4 o;
    o.x = f2bf(v.x); o.y = f2bf(v.y); o.z = f2bf(v.z); o.w = f2bf(v.w);
    *(ushort4*)(hsb + (size_t)i * 4) = o;
    return;
  }
  b -= ncv;
  __shared__ float tile[32][33];
  const int nwq = (NQ / 32) * (HID / 32);     // 11520
  const int nwkv = (NKVD / 32) * (HID / 32);  // 1440
  const float* in; u16* out; int R, C, bx, by;
  if (b < nwq) {
    in = wq; out = wqt; R = HID; C = NQ;
    int nx = NQ / 32; bx = (b % nx) * 32; by = (b / nx) * 32;
  } else if (b < nwq + nwkv) {
    b -= nwq; in = wk; out = wkt; R = HID; C = NKVD;
    int nx = NKVD / 32; bx = (b % nx) * 32; by = (b / nx) * 32;
  } else if (b < nwq + 2 * nwkv) {
    b -= nwq + nwkv; in = wv; out = wvt; R = HID; C = NKVD;
    int nx = NKVD / 32; bx = (b % nx) * 32; by = (b / nx) * 32;
  } else {
    b -= nwq + 2 * nwkv; in = wo; out = wot; R = NQ; C = HID;
    int nx = HID / 32; bx = (b % nx) * 32; by = (b / nx) * 32;
  }
  int tx = threadIdx.x & 31, ty = threadIdx.x >> 5;
#pragma unroll
  for (int i = 0; i < 4; ++i)
    tile[ty + i * 8][tx] = in[(long)(by + ty + i * 8) * C + bx + tx];
  __syncthreads();
#pragma unroll
  for (int i = 0; i < 4; ++i)
    out[(long)(bx + ty + i * 8) * R + by + tx] = f2bf(tile[tx][ty + i * 8]);
}

// ---------------- 128x128 bf16 MFMA GEMM core, 8-WAVE BK=64 (r15; for qkv) ----------------
__device__ __forceinline__ void gemm_tile8_64(const u16* __restrict__ Abase, int lda,
                                              const u16* __restrict__ Bbase, int ldb,
                                              int kloop, floatx4 acc[2][4]) {
  __shared__ __align__(16) u16 As[2][128][64];
  __shared__ __align__(16) u16 Bs[2][128][64];
  const int t = threadIdx.x;            // 0..511
  const int w = t >> 6, l = t & 63;
  const int sr = l >> 3;                // row within an 8-row gl2lds chunk
  const int ss = ((l & 7) ^ sr) * 8;    // pre-swizzled source slot (elems)
  const int wr = (w >> 1) * 32, wc = (w & 1) * 64;
  const int fr = l & 15, g = l >> 4;
  const int fsw = fr & 7;               // read-side row XOR
  floatx4 zero = {0.f, 0.f, 0.f, 0.f};
#pragma unroll
  for (int i = 0; i < 2; ++i)
#pragma unroll
    for (int j = 0; j < 4; ++j) acc[i][j] = zero;

  const u16* Ar0 = Abase + (long)(w * 16 + sr) * lda + ss;
  const u16* Ar1 = Abase + (long)(w * 16 + 8 + sr) * lda + ss;
  const u16* Br0 = Bbase + (long)(w * 16 + sr) * ldb + ss;
  const u16* Br1 = Bbase + (long)(w * 16 + 8 + sr) * ldb + ss;

#define STAGE64(buf, kt) do {                            \
    long ko_ = (long)(kt) * 64;                          \
    gl2lds16(Ar0 + ko_, &As[buf][w * 16][0]);            \
    gl2lds16(Ar1 + ko_, &As[buf][w * 16 + 8][0]);        \
    gl2lds16(Br0 + ko_, &Bs[buf][w * 16][0]);            \
    gl2lds16(Br1 + ko_, &Bs[buf][w * 16 + 8][0]);        \
  } while (0)

  const int nk = kloop >> 6;            // 45
  STAGE64(0, 0);
  for (int kt = 0; kt < nk; ++kt) {
    const int cb = kt & 1;
    asm volatile("s_waitcnt vmcnt(0)" ::: "memory");  // tile kt landed
    asm volatile("s_barrier" ::: "memory");           // kt ready; buf(kt-1) free
    if (kt + 1 < nk) STAGE64(cb ^ 1, kt + 1);
    short8 af[2][2], bf8[4][2];
#pragma unroll
    for (int i = 0; i < 2; ++i)
#pragma unroll
      for (int kk = 0; kk < 2; ++kk)
        af[i][kk] = *(const short8*)&As[cb][wr + i * 16 + fr][((kk * 4 + g) ^ fsw) * 8];
#pragma unroll
    for (int j = 0; j < 4; ++j)
#pragma unroll
      for (int kk = 0; kk < 2; ++kk)
        bf8[j][kk] = *(const short8*)&Bs[cb][wc + j * 16 + fr][((kk * 4 + g) ^ fsw) * 8];
#pragma unroll
    for (int i = 0; i < 2; ++i)
#pragma unroll
      for (int j = 0; j < 4; ++j)
#pragma unroll
        for (int kk = 0; kk < 2; ++kk)
          acc[i][j] = __builtin_amdgcn_mfma_f32_16x16x32_bf16(
              af[i][kk], bf8[j][kk], acc[i][j], 0, 0, 0);
  }
#undef STAGE64
}

// ---------------- QKV GEMM + bias + fused RoPE (8-wave BK=64, r15 unchanged) ----------------
__global__ __launch_bounds__(512) void k_gemm_qkv(
    const u16* __restrict__ hsb, const u16* __restrict__ wqt,
    const u16* __restrict__ wkt, const u16* __restrict__ wvt,
    const float* __restrict__ bq, const float* __restrict__ bk, const float* __restrict__ bv,
    const float* __restrict__ cosb, const float* __restrict__ sinb,
    u16* __restrict__ qbuf, u16* __restrict__ kbuf, u16* __restrict__ vtbuf) {
  int xcd = blockIdx.x & 7, lid = blockIdx.x >> 3;   // 640 blocks: 80/XCD
  int bm = ((xcd & 1) * 8 + (lid & 7)) * 128;        // balanced 8x10 per-XCD chunk
  int bn = ((xcd >> 1) * 10 + (lid >> 3)) * 128;     // (r13: FETCH 146->91 MB)
  const u16* Bt; const float* bias;
  if (bn < NQ)              { Bt = wqt + (long)bn * HID;               bias = bq + bn; }
  else if (bn < NQ + NKVD)  { Bt = wkt + (long)(bn - NQ) * HID;        bias = bk + (bn - NQ); }
  else                      { Bt = wvt + (long)(bn - NQ - NKVD) * HID; bias = bv + (bn - NQ - NKVD); }
  floatx4 acc[2][4];
  gemm_tile8_64(hsb + (long)bm * HID, HID, Bt, HID, HID, acc);
  int t = threadIdx.x, w = t >> 6, l = t & 63;
  int wr = (w >> 1) * 32, wc = (w & 1) * 64, fr = l & 15, fq = (l >> 4) * 4;
  if (bn < NQ + NKVD) {
    int ng0 = bn + wc;                         // head base (64-aligned)
    u16* hbase;
    if (ng0 < NQ) hbase = qbuf + (long)(ng0 >> 6) * S_LEN * HD;
    else          hbase = kbuf + (long)((ng0 - NQ) >> 6) * S_LEN * HD;
#pragma unroll
    for (int i = 0; i < 2; ++i)
#pragma unroll
      for (int r = 0; r < 4; ++r) {
        int srow = bm + wr + i * 16 + fq + r;
        const float* crow = cosb + (long)srow * HD;
        const float* srw  = sinb + (long)srow * HD;
#pragma unroll
        for (int j = 0; j < 2; ++j) {
          int dlo = j * 16 + fr;               // in [0,32)
          float c  = crow[dlo];
          float si = srw[dlo];
          float xl = acc[i][j][r]     + bias[wc + j * 16 + fr];
          float xh = acc[i][j + 2][r] + bias[wc + (j + 2) * 16 + fr];
          hbase[(long)srow * HD + dlo]      = f2bf(xl * c - xh * si);
          hbase[(long)srow * HD + dlo + 32] = f2bf(xh * c + xl * si);
        }
      }
  } else {
    // v path: transposed scatter vtbuf[kvh][d][s]
#pragma unroll
    for (int i = 0; i < 2; ++i)
#pragma unroll
      for (int j = 0; j < 4; ++j) {
        int ncol = wc + j * 16 + fr;
        int n3 = bn + ncol - NQ - NKVD;
        float bsv = bias[ncol];
#pragma unroll
        for (int r = 0; r < 4; ++r) {
          int srow = bm + wr + i * 16 + fq + r;
          vtbuf[(long)(n3 >> 6) * HD * S_LEN + (long)(n3 & 63) * S_LEN + srow] =
              f2bf(acc[i][j][r] + bsv);
        }
      }
  }
}

// ---------------- sliding-window GQA attention, QBLK=128 (r16, unchanged) ----------------
__global__ __launch_bounds__(512) void k_attn(
    const u16* __restrict__ qb, const u16* __restrict__ kb, const u16* __restrict__ vtb,
    const float* __restrict__ sinks, u16* __restrict__ ao) {
  __shared__ __align__(16) u16 KP[21504];   // K [256][72] / P [8][16][168]
  __shared__ __align__(16) u16 Vl[64][280];
  int t = threadIdx.x;
  int h = blockIdx.y, kvh = h >> 3;
  int qs = blockIdx.x * 128;
  int kstart = qs - 128;
  const u16* kbase = kb + (long)kvh * S_LEN * HD;
  const u16* vbase = vtb + (long)kvh * HD * S_LEN;
#pragma unroll
  for (int it = 0; it < 4; ++it) {        // K: 256 rows x 64 d = 2048 vec8
    int idx = t + it * 512;
    int c = idx >> 3, dc = (idx & 7) * 8;
    int j = kstart + c;
    short8 v = {0, 0, 0, 0, 0, 0, 0, 0};
    if (j >= 0) v = *(const short8*)(kbase + (long)j * HD + dc);
    *(short8*)&KP[c * 72 + dc] = v;
  }
#pragma unroll
  for (int it = 0; it < 5; ++it) {        // Vt: 64 rows x 280 cols = 2240 vec8
    int idx = t + it * 512;
    if (idx < 2240) {
      int d = idx / 35, c8 = idx % 35;
      int c = c8 * 8;
      int j = kstart + c;
      short8 v = {0, 0, 0, 0, 0, 0, 0, 0};
      if (c < 256 && j >= 0) v = *(const short8*)(vbase + (long)d * S_LEN + j);
      *(short8*)&Vl[d][c] = v;
    }
  }
  __syncthreads();

  int w = t >> 6, l = t & 63;
  int fr = l & 15, fk8 = (l >> 4) * 8, fq = (l >> 4) * 4;
  const u16* qrow = qb + (long)h * S_LEN * HD + (long)(qs + w * 16 + fr) * HD;
  short8 a0 = *(const short8*)(qrow + fk8);
  short8 a1 = *(const short8*)(qrow + 32 + fk8);
  floatx4 sc[9];
#pragma unroll
  for (int ct = 0; ct < 9; ++ct) {
    const u16* kr = &KP[(w * 16 + ct * 16 + fr) * 72];
    short8 b0 = *(const short8*)(kr + fk8);
    short8 b1 = *(const short8*)(kr + 32 + fk8);
    floatx4 z = {0.f, 0.f, 0.f, 0.f};
    z = __builtin_amdgcn_mfma_f32_16x16x32_bf16(a0, b0, z, 0, 0, 0);
    z = __builtin_amdgcn_mfma_f32_16x16x32_bf16(a1, b1, z, 0, 0, 0);
    sc[ct] = z;
  }
  __syncthreads();  // all waves done reading K region before P overwrites it

  u16* Pw = KP + w * (16 * 168);          // per-wave P tile [16][168]
  float snk = sinks[h];
#pragma unroll
  for (int r = 0; r < 4; ++r) {
    int rloc = fq + r;                    // query index within wave's 16
    int cmin = rloc + 1;                  // i-j < 128 (wave-local cols)
    int jmin = 128 - qs - w * 16;         // j >= 0
    if (jmin > cmin) cmin = jmin;
    int cmax = rloc + 128;                // j <= i
    float vals[9];
    float mx = snk;
#pragma unroll
    for (int ct = 0; ct < 9; ++ct) {
      int c = ct * 16 + fr;
      float v = (c >= cmin && c <= cmax) ? sc[ct][r] * SCALE : -1e30f;
      vals[ct] = v;
      mx = fmaxf(mx, v);
    }
#pragma unroll
    for (int m = 1; m < 16; m <<= 1) mx = fmaxf(mx, __shfl_xor(mx, m));
    float e[9], sum = 0.f;
#pragma unroll
    for (int ct = 0; ct < 9; ++ct) { e[ct] = __expf(vals[ct] - mx); sum += e[ct]; }
#pragma unroll
    for (int m = 1; m < 16; m <<= 1) sum += __shfl_xor(sum, m);
    sum += __expf(snk - mx);
    float inv = 1.f / sum;
#pragma unroll
    for (int ct = 0; ct < 9; ++ct)
      Pw[rloc * 168 + ct * 16 + fr] = f2bf(e[ct] * inv);
    Pw[rloc * 168 + 144 + fr] = 0;        // zero-pad cols 144..159 for kk tiling
  }
  __syncthreads();

  floatx4 o[4];
  floatx4 zero = {0.f, 0.f, 0.f, 0.f};
#pragma unroll
  for (int cd = 0; cd < 4; ++cd) o[cd] = zero;
#pragma unroll
  for (int kk = 0; kk < 5; ++kk) {
    short8 pa = *(const short8*)(Pw + fr * 168 + kk * 32 + fk8);
#pragma unroll
    for (int cd = 0; cd < 4; ++cd) {
      short8 bv8 = *(const short8*)&Vl[cd * 16 + fr][w * 16 + kk * 32 + fk8];
      o[cd] = __builtin_amdgcn_mfma_f32_16x16x32_bf16(pa, bv8, o[cd], 0, 0, 0);
    }
  }
#pragma unroll
  for (int cd = 0; cd < 4; ++cd)
#pragma unroll
    for (int r = 0; r < 4; ++r) {
      int srow = qs + w * 16 + fq + r;
      ao[(long)srow * NQ + h * HD + cd * 16 + fr] = f2bf(o[cd][r]);
    }
}

// ---------------- output projection GEMM: BK=64, 2-buffer, balanced XCD (r17) ----------------
// r16 PMC: dur ~= FETCH/1.37TB/s -> traffic-bound. Old mapping gave each XCD
// all 16 bm (full 16.8 MB A) + ~3 bn of B ~= 19.8 MB/XCD. Balanced 2x4
// partition (qkv's r13 fix): XCD gets 8 bm x 6 bn -> A 8.4 + B 6.3 = 14.7 MB.
// Grid padded to 384 = 8 XCD x 48; bnx>=23 blocks exit early (16 idle).
// Pure index remap; K-order per output element unchanged -> bit-identical.
__global__ __launch_bounds__(256) void k_gemm_out(
    const u16* __restrict__ attn, const u16* __restrict__ wot,
    const float* __restrict__ bo, float* __restrict__ out) {
  __shared__ __align__(16) u16 As[2][128][64];
  __shared__ __align__(16) u16 Bs[2][128][64];
  int xcd = blockIdx.x & 7, lid = blockIdx.x >> 3;   // 48 per XCD
  int bm = (((xcd & 1) * 8) + (lid & 7)) * 128;      // 2 bm-groups of 8
  int bnx = (xcd >> 1) * 6 + (lid >> 3);             // 4 bn-groups of 6 (last 5)
  if (bnx >= 23) return;
  int bn = bnx * 128;

  const int t = threadIdx.x;
  const int w = t >> 6, l = t & 63;
  const int sr = l >> 3;                      // row within 8-row chunk
  const int ss = ((l & 7) ^ sr) * 8;          // pre-swizzled source slot (elems)
  const int wr = (w >> 1) * 64, wc = (w & 1) * 64;
  const int fr = l & 15, g = l >> 4;
  const int fsw = fr & 7;                     // read-side row XOR

  const u16* Ar = attn + (long)bm * NQ;
  const u16* Br = wot + (long)bn * NQ;

  floatx4 acc[4][4];
  floatx4 zero = {0.f, 0.f, 0.f, 0.f};
#pragma unroll
  for (int i = 0; i < 4; ++i)
#pragma unroll
    for (int j = 0; j < 4; ++j) acc[i][j] = zero;

#define OSTAGE(buf, kt) do {                                          \
    long ko_ = (long)(kt) * 64 + ss;                                  \
    _Pragma("unroll")                                                 \
    for (int c8 = 0; c8 < 4; ++c8) {                                  \
      int r0 = w * 32 + c8 * 8;                                       \
      gl2lds16(Ar + (long)(r0 + sr) * NQ + ko_, &As[buf][r0][0]);     \
      gl2lds16(Br + (long)(r0 + sr) * NQ + ko_, &Bs[buf][r0][0]);     \
    } } while (0)

  const int nk = NQ >> 6;                     // 64
  OSTAGE(0, 0);
  for (int kt = 0; kt < nk; ++kt) {
    const int cb = kt & 1;
    asm volatile("s_waitcnt vmcnt(0)" ::: "memory");  // tile kt landed (prefetched)
    asm volatile("s_barrier" ::: "memory");           // all waves: kt ready, kt-1 free
    if (kt + 1 < nk) OSTAGE(cb ^ 1, kt + 1);
    short8 af[4][2], bf8[4][2];
#pragma unroll
    for (int i = 0; i < 4; ++i)
#pragma unroll
      for (int kk = 0; kk < 2; ++kk)
        af[i][kk] = *(const short8*)&As[cb][wr + i * 16 + fr][((kk * 4 + g) ^ fsw) * 8];
#pragma unroll
    for (int j = 0; j < 4; ++j)
#pragma unroll
      for (int kk = 0; kk < 2; ++kk)
        bf8[j][kk] = *(const short8*)&Bs[cb][wc + j * 16 + fr][((kk * 4 + g) ^ fsw) * 8];
#pragma unroll
    for (int i = 0; i < 4; ++i)
#pragma unroll
      for (int j = 0; j < 4; ++j)
#pragma unroll
        for (int kk = 0; kk < 2; ++kk)
          acc[i][j] = __builtin_amdgcn_mfma_f32_16x16x32_bf16(
              af[i][kk], bf8[j][kk], acc[i][j], 0, 0, 0);
  }
#undef OSTAGE

  int fqe = (l >> 4) * 4;
#pragma unroll
  for (int i = 0; i < 4; ++i)
#pragma unroll
    for (int j = 0; j < 4; ++j) {
      int ng = bn + wc + j * 16 + fr;
      if (ng >= HID) continue;            // N=2880 tail guard
      float bsv = bo[ng];
#pragma unroll
      for (int r = 0; r < 4; ++r) {
        int srow = bm + wr + i * 16 + fqe + r;
        out[(long)srow * HID + ng] = acc[i][j][r] + bsv;
      }
    }
}

extern "C" void kernel_launch(void* const* d_in, const int* in_sizes, int n_in,
                              void* d_out, int out_size, void* d_ws, size_t ws_size,
                              hipStream_t stream) {
  const float* hs    = (const float*)d_in[0];
  const float* cosb  = (const float*)d_in[1];
  const float* sinb  = (const float*)d_in[2];
  const float* wq    = (const float*)d_in[3];
  const float* bq    = (const float*)d_in[4];
  const float* wk    = (const float*)d_in[5];
  const float* bk    = (const float*)d_in[6];
  const float* wv    = (const float*)d_in[7];
  const float* bv    = (const float*)d_in[8];
  const float* wo    = (const float*)d_in[9];
  const float* bo    = (const float*)d_in[10];
  const float* sinks = (const float*)d_in[11];
  float* out = (float*)d_out;

  char* p = (char*)d_ws;
  u16* hsb   = (u16*)p; p += (size_t)S_LEN * HID * 2;
  u16* wqt   = (u16*)p; p += (size_t)NQ * HID * 2;
  u16* wkt   = (u16*)p; p += (size_t)NKVD * HID * 2;
  u16* wvt   = (u16*)p; p += (size_t)NKVD * HID * 2;
  u16* wot   = (u16*)p; p += (size_t)2944 * NQ * 2;
  u16* qbuf  = (u16*)p; p += (size_t)NH * S_LEN * HD * 2;
  u16* kbuf  = (u16*)p; p += (size_t)NKV * S_LEN * HD * 2;
  u16* vtbuf = (u16*)p; p += (size_t)NKV * HD * S_LEN * 2;
  u16* abuf  = (u16*)p; p += (size_t)S_LEN * NQ * 2;

  const int npre = (S_LEN * HID / 4) / 256 +
                   (NQ / 32) * (HID / 32) * 2 + (NKVD / 32) * (HID / 32) * 2;  // 31680
  k_pre<<<npre, 256, 0, stream>>>(hs, hsb, wq, wk, wv, wo, wqt, wkt, wvt, wot);
  k_gemm_qkv<<<(NQ + 2 * NKVD) / 128 * (S_LEN / 128), 512, 0, stream>>>(
      hsb, wqt, wkt, wvt, bq, bk, bv, cosb, sinb, qbuf, kbuf, vtbuf);
  k_attn<<<dim3(S_LEN / 128, NH), 512, 0, stream>>>(qbuf, kbuf, vtbuf, sinks, abuf);
  k_gemm_out<<<8 * 48, 256, 0, stream>>>(abuf, wot, bo, out);
}

// Round 18
// 179.766 us; speedup vs baseline: 1.0497x; 1.0497x over previous
//
#include <hip/hip_runtime.h>
#include <hip/hip_bf16.h>
#include <stdint.h>

#define S_LEN 2048
#define HID 2880
#define NH 64
#define NKV 8
#define HD 64
#define NQ (NH * HD)     // 4096
#define NKVD (NKV * HD)  // 512
#define SCALE 0.125f

typedef unsigned short u16;
typedef __attribute__((ext_vector_type(8))) short short8;
typedef __attribute__((ext_vector_type(4))) float floatx4;

__device__ __forceinline__ u16 f2bf(float f) {
  union { float f; unsigned u; } x; x.f = f;
  unsigned r = x.u + 0x7fffu + ((x.u >> 16) & 1u);
  return (u16)(r >> 16);
}

// bijective XCD-aware block swizzle (m204): contiguous chunk per XCD
__device__ __forceinline__ int xcd_swz(int orig, int nwg) {
  int q = nwg >> 3, r = nwg & 7, xcd = orig & 7, lid = orig >> 3;
  return (xcd < r ? xcd * (q + 1) : r * (q + 1) + (xcd - r) * q) + lid;
}

// global -> LDS async copy, 16B per lane. LDS dest is wave-uniform base;
// HW writes lane i at base + i*16.
__device__ __forceinline__ void gl2lds16(const void* g, void* l) {
  __builtin_amdgcn_global_load_lds(
      (__attribute__((address_space(1))) unsigned int*)(uintptr_t)g,
      (__attribute__((address_space(3))) unsigned int*)(unsigned int)(uintptr_t)l,
      16, 0, 0);
}

// ---------------- merged preprocessing: hs convert + all 4 transposes ----------------
__global__ void k_pre(const float* __restrict__ hs, u16* __restrict__ hsb,
                      const float* __restrict__ wq, const float* __restrict__ wk,
                      const float* __restrict__ wv, const float* __restrict__ wo,
                      u16* __restrict__ wqt, u16* __restrict__ wkt,
                      u16* __restrict__ wvt, u16* __restrict__ wot) {
  int b = blockIdx.x;
  const int ncv = (S_LEN * HID / 4) / 256;    // 5760 convert blocks
  if (b < ncv) {
    int i = b * 256 + threadIdx.x;
    float4 v = ((const float4*)hs)[i];
    ushort4 o;
    o.x = f2bf(v.x); o.y = f2bf(v.y); o.z = f2bf(v.z); o.w = f2bf(v.w);
    *(ushort4*)(hsb + (size_t)i * 4) = o;
    return;
  }
  b -= ncv;
  __shared__ float tile[32][33];
  const int nwq = (NQ / 32) * (HID / 32);     // 11520
  const int nwkv = (NKVD / 32) * (HID / 32);  // 1440
  const float* in; u16* out; int R, C, bx, by;
  if (b < nwq) {
    in = wq; out = wqt; R = HID; C = NQ;
    int nx = NQ / 32; bx = (b % nx) * 32; by = (b / nx) * 32;
  } else if (b < nwq + nwkv) {
    b -= nwq; in = wk; out = wkt; R = HID; C = NKVD;
    int nx = NKVD / 32; bx = (b % nx) * 32; by = (b / nx) * 32;
  } else if (b < nwq + 2 * nwkv) {
    b -= nwq + nwkv; in = wv; out = wvt; R = HID; C = NKVD;
    int nx = NKVD / 32; bx = (b % nx) * 32; by = (b / nx) * 32;
  } else {
    b -= nwq + 2 * nwkv; in = wo; out = wot; R = NQ; C = HID;
    int nx = HID / 32; bx = (b % nx) * 32; by = (b / nx) * 32;
  }
  int tx = threadIdx.x & 31, ty = threadIdx.x >> 5;
#pragma unroll
  for (int i = 0; i < 4; ++i)
    tile[ty + i * 8][tx] = in[(long)(by + ty + i * 8) * C + bx + tx];
  __syncthreads();
#pragma unroll
  for (int i = 0; i < 4; ++i)
    out[(long)(bx + ty + i * 8) * R + by + tx] = f2bf(tile[tx][ty + i * 8]);
}

// ---------------- 128x128 bf16 MFMA GEMM core, 8-WAVE BK=64 (r15) ----------------
// Shared by qkv AND (r18) out-GEMM. 512 threads / 8 waves, wave-tile 32x64;
// 2-buffer 64 KB LDS; one barrier per 64-K; stage(t+1) right after barrier(t)
// into the buffer freed by compute(t-1) (race-free); vmcnt(0) covered by a
// full K-step of prefetch flight + 16 waves/CU of TLP.
__device__ __forceinline__ void gemm_tile8_64(const u16* __restrict__ Abase, int lda,
                                              const u16* __restrict__ Bbase, int ldb,
                                              int kloop, floatx4 acc[2][4]) {
  __shared__ __align__(16) u16 As[2][128][64];
  __shared__ __align__(16) u16 Bs[2][128][64];
  const int t = threadIdx.x;            // 0..511
  const int w = t >> 6, l = t & 63;
  const int sr = l >> 3;                // row within an 8-row gl2lds chunk
  const int ss = ((l & 7) ^ sr) * 8;    // pre-swizzled source slot (elems)
  const int wr = (w >> 1) * 32, wc = (w & 1) * 64;
  const int fr = l & 15, g = l >> 4;
  const int fsw = fr & 7;               // read-side row XOR
  floatx4 zero = {0.f, 0.f, 0.f, 0.f};
#pragma unroll
  for (int i = 0; i < 2; ++i)
#pragma unroll
    for (int j = 0; j < 4; ++j) acc[i][j] = zero;

  const u16* Ar0 = Abase + (long)(w * 16 + sr) * lda + ss;
  const u16* Ar1 = Abase + (long)(w * 16 + 8 + sr) * lda + ss;
  const u16* Br0 = Bbase + (long)(w * 16 + sr) * ldb + ss;
  const u16* Br1 = Bbase + (long)(w * 16 + 8 + sr) * ldb + ss;

#define STAGE64(buf, kt) do {                            \
    long ko_ = (long)(kt) * 64;                          \
    gl2lds16(Ar0 + ko_, &As[buf][w * 16][0]);            \
    gl2lds16(Ar1 + ko_, &As[buf][w * 16 + 8][0]);        \
    gl2lds16(Br0 + ko_, &Bs[buf][w * 16][0]);            \
    gl2lds16(Br1 + ko_, &Bs[buf][w * 16 + 8][0]);        \
  } while (0)

  const int nk = kloop >> 6;
  STAGE64(0, 0);
  for (int kt = 0; kt < nk; ++kt) {
    const int cb = kt & 1;
    asm volatile("s_waitcnt vmcnt(0)" ::: "memory");  // tile kt landed
    asm volatile("s_barrier" ::: "memory");           // kt ready; buf(kt-1) free
    if (kt + 1 < nk) STAGE64(cb ^ 1, kt + 1);
    short8 af[2][2], bf8[4][2];
#pragma unroll
    for (int i = 0; i < 2; ++i)
#pragma unroll
      for (int kk = 0; kk < 2; ++kk)
        af[i][kk] = *(const short8*)&As[cb][wr + i * 16 + fr][((kk * 4 + g) ^ fsw) * 8];
#pragma unroll
    for (int j = 0; j < 4; ++j)
#pragma unroll
      for (int kk = 0; kk < 2; ++kk)
        bf8[j][kk] = *(const short8*)&Bs[cb][wc + j * 16 + fr][((kk * 4 + g) ^ fsw) * 8];
#pragma unroll
    for (int i = 0; i < 2; ++i)
#pragma unroll
      for (int j = 0; j < 4; ++j)
#pragma unroll
        for (int kk = 0; kk < 2; ++kk)
          acc[i][j] = __builtin_amdgcn_mfma_f32_16x16x32_bf16(
              af[i][kk], bf8[j][kk], acc[i][j], 0, 0, 0);
  }
#undef STAGE64
}

// ---------------- QKV GEMM + bias + fused RoPE (8-wave BK=64, r15 unchanged) ----------------
__global__ __launch_bounds__(512) void k_gemm_qkv(
    const u16* __restrict__ hsb, const u16* __restrict__ wqt,
    const u16* __restrict__ wkt, const u16* __restrict__ wvt,
    const float* __restrict__ bq, const float* __restrict__ bk, const float* __restrict__ bv,
    const float* __restrict__ cosb, const float* __restrict__ sinb,
    u16* __restrict__ qbuf, u16* __restrict__ kbuf, u16* __restrict__ vtbuf) {
  int xcd = blockIdx.x & 7, lid = blockIdx.x >> 3;   // 640 blocks: 80/XCD
  int bm = ((xcd & 1) * 8 + (lid & 7)) * 128;        // balanced 8x10 per-XCD chunk
  int bn = ((xcd >> 1) * 10 + (lid >> 3)) * 128;     // (r13: FETCH 146->91 MB)
  const u16* Bt; const float* bias;
  if (bn < NQ)              { Bt = wqt + (long)bn * HID;               bias = bq + bn; }
  else if (bn < NQ + NKVD)  { Bt = wkt + (long)(bn - NQ) * HID;        bias = bk + (bn - NQ); }
  else                      { Bt = wvt + (long)(bn - NQ - NKVD) * HID; bias = bv + (bn - NQ - NKVD); }
  floatx4 acc[2][4];
  gemm_tile8_64(hsb + (long)bm * HID, HID, Bt, HID, HID, acc);
  int t = threadIdx.x, w = t >> 6, l = t & 63;
  int wr = (w >> 1) * 32, wc = (w & 1) * 64, fr = l & 15, fq = (l >> 4) * 4;
  if (bn < NQ + NKVD) {
    int ng0 = bn + wc;                         // head base (64-aligned)
    u16* hbase;
    if (ng0 < NQ) hbase = qbuf + (long)(ng0 >> 6) * S_LEN * HD;
    else          hbase = kbuf + (long)((ng0 - NQ) >> 6) * S_LEN * HD;
#pragma unroll
    for (int i = 0; i < 2; ++i)
#pragma unroll
      for (int r = 0; r < 4; ++r) {
        int srow = bm + wr + i * 16 + fq + r;
        const float* crow = cosb + (long)srow * HD;
        const float* srw  = sinb + (long)srow * HD;
#pragma unroll
        for (int j = 0; j < 2; ++j) {
          int dlo = j * 16 + fr;               // in [0,32)
          float c  = crow[dlo];
          float si = srw[dlo];
          float xl = acc[i][j][r]     + bias[wc + j * 16 + fr];
          float xh = acc[i][j + 2][r] + bias[wc + (j + 2) * 16 + fr];
          hbase[(long)srow * HD + dlo]      = f2bf(xl * c - xh * si);
          hbase[(long)srow * HD + dlo + 32] = f2bf(xh * c + xl * si);
        }
      }
  } else {
    // v path: transposed scatter vtbuf[kvh][d][s]
#pragma unroll
    for (int i = 0; i < 2; ++i)
#pragma unroll
      for (int j = 0; j < 4; ++j) {
        int ncol = wc + j * 16 + fr;
        int n3 = bn + ncol - NQ - NKVD;
        float bsv = bias[ncol];
#pragma unroll
        for (int r = 0; r < 4; ++r) {
          int srow = bm + wr + i * 16 + fq + r;
          vtbuf[(long)(n3 >> 6) * HD * S_LEN + (long)(n3 & 63) * S_LEN + srow] =
              f2bf(acc[i][j][r] + bsv);
        }
      }
  }
}

// ---------------- sliding-window GQA attention, QBLK=128 (r16, unchanged) ----------------
__global__ __launch_bounds__(512) void k_attn(
    const u16* __restrict__ qb, const u16* __restrict__ kb, const u16* __restrict__ vtb,
    const float* __restrict__ sinks, u16* __restrict__ ao) {
  __shared__ __align__(16) u16 KP[21504];   // K [256][72] / P [8][16][168]
  __shared__ __align__(16) u16 Vl[64][280];
  int t = threadIdx.x;
  int h = blockIdx.y, kvh = h >> 3;
  int qs = blockIdx.x * 128;
  int kstart = qs - 128;
  const u16* kbase = kb + (long)kvh * S_LEN * HD;
  const u16* vbase = vtb + (long)kvh * HD * S_LEN;
#pragma unroll
  for (int it = 0; it < 4; ++it) {        // K: 256 rows x 64 d = 2048 vec8
    int idx = t + it * 512;
    int c = idx >> 3, dc = (idx & 7) * 8;
    int j = kstart + c;
    short8 v = {0, 0, 0, 0, 0, 0, 0, 0};
    if (j >= 0) v = *(const short8*)(kbase + (long)j * HD + dc);
    *(short8*)&KP[c * 72 + dc] = v;
  }
#pragma unroll
  for (int it = 0; it < 5; ++it) {        // Vt: 64 rows x 280 cols = 2240 vec8
    int idx = t + it * 512;
    if (idx < 2240) {
      int d = idx / 35, c8 = idx % 35;
      int c = c8 * 8;
      int j = kstart + c;
      short8 v = {0, 0, 0, 0, 0, 0, 0, 0};
      if (c < 256 && j >= 0) v = *(const short8*)(vbase + (long)d * S_LEN + j);
      *(short8*)&Vl[d][c] = v;
    }
  }
  __syncthreads();

  int w = t >> 6, l = t & 63;
  int fr = l & 15, fk8 = (l >> 4) * 8, fq = (l >> 4) * 4;
  const u16* qrow = qb + (long)h * S_LEN * HD + (long)(qs + w * 16 + fr) * HD;
  short8 a0 = *(const short8*)(qrow + fk8);
  short8 a1 = *(const short8*)(qrow + 32 + fk8);
  floatx4 sc[9];
#pragma unroll
  for (int ct = 0; ct < 9; ++ct) {
    const u16* kr = &KP[(w * 16 + ct * 16 + fr) * 72];
    short8 b0 = *(const short8*)(kr + fk8);
    short8 b1 = *(const short8*)(kr + 32 + fk8);
    floatx4 z = {0.f, 0.f, 0.f, 0.f};
    z = __builtin_amdgcn_mfma_f32_16x16x32_bf16(a0, b0, z, 0, 0, 0);
    z = __builtin_amdgcn_mfma_f32_16x16x32_bf16(a1, b1, z, 0, 0, 0);
    sc[ct] = z;
  }
  __syncthreads();  // all waves done reading K region before P overwrites it

  u16* Pw = KP + w * (16 * 168);          // per-wave P tile [16][168]
  float snk = sinks[h];
#pragma unroll
  for (int r = 0; r < 4; ++r) {
    int rloc = fq + r;                    // query index within wave's 16
    int cmin = rloc + 1;                  // i-j < 128 (wave-local cols)
    int jmin = 128 - qs - w * 16;         // j >= 0
    if (jmin > cmin) cmin = jmin;
    int cmax = rloc + 128;                // j <= i
    float vals[9];
    float mx = snk;
#pragma unroll
    for (int ct = 0; ct < 9; ++ct) {
      int c = ct * 16 + fr;
      float v = (c >= cmin && c <= cmax) ? sc[ct][r] * SCALE : -1e30f;
      vals[ct] = v;
      mx = fmaxf(mx, v);
    }
#pragma unroll
    for (int m = 1; m < 16; m <<= 1) mx = fmaxf(mx, __shfl_xor(mx, m));
    float e[9], sum = 0.f;
#pragma unroll
    for (int ct = 0; ct < 9; ++ct) { e[ct] = __expf(vals[ct] - mx); sum += e[ct]; }
#pragma unroll
    for (int m = 1; m < 16; m <<= 1) sum += __shfl_xor(sum, m);
    sum += __expf(snk - mx);
    float inv = 1.f / sum;
#pragma unroll
    for (int ct = 0; ct < 9; ++ct)
      Pw[rloc * 168 + ct * 16 + fr] = f2bf(e[ct] * inv);
    Pw[rloc * 168 + 144 + fr] = 0;        // zero-pad cols 144..159 for kk tiling
  }
  __syncthreads();

  floatx4 o[4];
  floatx4 zero = {0.f, 0.f, 0.f, 0.f};
#pragma unroll
  for (int cd = 0; cd < 4; ++cd) o[cd] = zero;
#pragma unroll
  for (int kk = 0; kk < 5; ++kk) {
    short8 pa = *(const short8*)(Pw + fr * 168 + kk * 32 + fk8);
#pragma unroll
    for (int cd = 0; cd < 4; ++cd) {
      short8 bv8 = *(const short8*)&Vl[cd * 16 + fr][w * 16 + kk * 32 + fk8];
      o[cd] = __builtin_amdgcn_mfma_f32_16x16x32_bf16(pa, bv8, o[cd], 0, 0, 0);
    }
  }
#pragma unroll
  for (int cd = 0; cd < 4; ++cd)
#pragma unroll
    for (int r = 0; r < 4; ++r) {
      int srow = qs + w * 16 + fq + r;
      ao[(long)srow * NQ + h * HD + cd * 16 + fr] = f2bf(o[cd][r]);
    }
}

// ---------------- output projection GEMM: 8-wave BK=64 core (r18) ----------------
// r17 proved out is LATENCY-bound (FETCH 104->61 MB, dur unchanged). The cover
// for a per-wave vmcnt(0) stall is TLP: qkv's identical-structure 8-wave core
// runs 775 TF at 16 waves/CU vs out's 4-wave 615 TF at ~5.75 waves/CU.
// Reuse gemm_tile8_64 verbatim; r16 xcd_swz mapping (its 78.4us was best).
// K-order per output element unchanged -> bit-identical.
__global__ __launch_bounds__(512) void k_gemm_out(
    const u16* __restrict__ attn, const u16* __restrict__ wot,
    const float* __restrict__ bo, float* __restrict__ out) {
  int sw = xcd_swz(blockIdx.x, gridDim.x);    // 368 blocks = 23 bn x 16 bm
  int bm = (sw & 15) * 128, bn = (sw >> 4) * 128;
  floatx4 acc[2][4];
  gemm_tile8_64(attn + (long)bm * NQ, NQ, wot + (long)bn * NQ, NQ, NQ, acc);
  int t = threadIdx.x, w = t >> 6, l = t & 63;
  int wr = (w >> 1) * 32, wc = (w & 1) * 64, fr = l & 15, fq = (l >> 4) * 4;
#pragma unroll
  for (int i = 0; i < 2; ++i)
#pragma unroll
    for (int j = 0; j < 4; ++j) {
      int ng = bn + wc + j * 16 + fr;
      if (ng >= HID) continue;            // N=2880 tail guard
      float bsv = bo[ng];
#pragma unroll
      for (int r = 0; r < 4; ++r) {
        int srow = bm + wr + i * 16 + fq + r;
        out[(long)srow * HID + ng] = acc[i][j][r] + bsv;
      }
    }
}

extern "C" void kernel_launch(void* const* d_in, const int* in_sizes, int n_in,
                              void* d_out, int out_size, void* d_ws, size_t ws_size,
                              hipStream_t stream) {
  const float* hs    = (const float*)d_in[0];
  const float* cosb  = (const float*)d_in[1];
  const float* sinb  = (const float*)d_in[2];
  const float* wq    = (const float*)d_in[3];
  const float* bq    = (const float*)d_in[4];
  const float* wk    = (const float*)d_in[5];
  const float* bk    = (const float*)d_in[6];
  const float* wv    = (const float*)d_in[7];
  const float* bv    = (const float*)d_in[8];
  const float* wo    = (const float*)d_in[9];
  const float* bo    = (const float*)d_in[10];
  const float* sinks = (const float*)d_in[11];
  float* out = (float*)d_out;

  char* p = (char*)d_ws;
  u16* hsb   = (u16*)p; p += (size_t)S_LEN * HID * 2;
  u16* wqt   = (u16*)p; p += (size_t)NQ * HID * 2;
  u16* wkt   = (u16*)p; p += (size_t)NKVD * HID * 2;
  u16* wvt   = (u16*)p; p += (size_t)NKVD * HID * 2;
  u16* wot   = (u16*)p; p += (size_t)2944 * NQ * 2;
  u16* qbuf  = (u16*)p; p += (size_t)NH * S_LEN * HD * 2;
  u16* kbuf  = (u16*)p; p += (size_t)NKV * S_LEN * HD * 2;
  u16* vtbuf = (u16*)p; p += (size_t)NKV * HD * S_LEN * 2;
  u16* abuf  = (u16*)p; p += (size_t)S_LEN * NQ * 2;

  const int npre = (S_LEN * HID / 4) / 256 +
                   (NQ / 32) * (HID / 32) * 2 + (NKVD / 32) * (HID / 32) * 2;  // 31680
  k_pre<<<npre, 256, 0, stream>>>(hs, hsb, wq, wk, wv, wo, wqt, wkt, wvt, wot);
  k_gemm_qkv<<<(NQ + 2 * NKVD) / 128 * (S_LEN / 128), 512, 0, stream>>>(
      hsb, wqt, wkt, wvt, bq, bk, bv, cosb, sinb, qbuf, kbuf, vtbuf);
  k_attn<<<dim3(S_LEN / 128, NH), 512, 0, stream>>>(qbuf, kbuf, vtbuf, sinks, abuf);
  k_gemm_out<<<23 * 16, 512, 0, stream>>>(abuf, wot, bo, out);
}